// Round 5
// baseline (189.806 us; speedup 1.0000x reference)
//
#include <hip/hip_runtime.h>
#include <hip/hip_bf16.h>

// Problem constants
#define B_   2
#define N_   2048
#define D_   128
#define H_   16
#define ALL_ 2048
#define M_   (B_*N_)    // 4096 total rows
#define BH_  (B_*H_)    // 32 (batch*heads)

typedef __bf16 bf16;
typedef __bf16 bf16x8 __attribute__((ext_vector_type(8)));
typedef __bf16 bf16x4 __attribute__((ext_vector_type(4)));
typedef float  floatx4 __attribute__((ext_vector_type(4)));

#define MFMA32K(a,b,c) __builtin_amdgcn_mfma_f32_16x16x32_bf16((a),(b),(c),0,0,0)

// async global->LDS DMA, 16B per lane (m97 pattern) — used by prep/qkv path.
__device__ inline void load_lds16(const bf16* g, bf16* l) {
    __builtin_amdgcn_global_load_lds((const __attribute__((address_space(1))) void*)g,
                                     (__attribute__((address_space(3))) void*)l, 16, 0, 0);
}

// ---------------------------------------------------------------------------
// FRAGMENT-MAJOR LAYOUTS:
//  A/B-frag canonical (16x16x32): elem j of lane (lrow=lane&15,quad=lane>>4)
//    A[m=lrow][k=kf*32+quad*8+j]  /  B[k=kf*32+quad*8+j][n=lrow]
//  Wf  (Wq/Wk/Wv): [ct 128][kf 4][lane][8]  canonical
//  xf:  [rt 256][kf 4][lane][8]             canonical
//  Qf/Kf: [bh][t 128][kf 4][lane][8]        canonical
//  Vf:  [bh][kb 32][nf 8][g 2][lane][8]  PERMUTED k:
//        elem j = V[key=kb*64+(2g+(j>>2))*16+quad*4+(j&3)][d=nf*16+lrow]
//  ctxf: [qt 256][kf 64][lane][8]        PERMUTED k (same map over d):
//        elem j = ctx[q=qt*16+lrow][d' = (kf&3)*32+(j>>2)*16+quad*4+(j&3)]
//        (head = kf>>2) — written DIRECTLY from flash O accumulators.
//  Wof: [ct 8][kf 64][lane][8]           PERMUTED k to MATCH ctxf:
//        elem j = Wo[k = kf*32+(j>>2)*16+quad*4+(j&3)][col=ct*16+lrow]
//  MFMA contraction is invariant when A and B agree on the k-permutation.
//  mbias pre-scaled by log2(e) (exp2 path).
// ---------------------------------------------------------------------------

// ---------------------------------------------------------------------------
// Kernel T: prep — unchanged.
// ---------------------------------------------------------------------------
__global__ __launch_bounds__(256) void prep_weights(const float* __restrict__ x,
                                                    const float* __restrict__ Wq,
                                                    const float* __restrict__ Wk,
                                                    const float* __restrict__ Wv,
                                                    const float* __restrict__ Wo,
                                                    const int* __restrict__ mask,
                                                    bf16* __restrict__ Wqf,
                                                    bf16* __restrict__ Wkf,
                                                    bf16* __restrict__ Wvf,
                                                    bf16* __restrict__ Wof,
                                                    bf16* __restrict__ xf,
                                                    float* __restrict__ mbias) {
    __shared__ bf16 pw[16896];
    int bid = blockIdx.x, t = threadIdx.x;
    int lane = t & 63, wave = t >> 6;
    int lrow = lane & 15, quad = lane >> 4;

    if (bid < 192) {
        // ---- Wq/Wk/Wv [128][2048]: block = 64 k-rows (half) x 64 cols ----
        int m = bid / 64, rest = bid % 64;
        int cg = rest >> 1, kh = rest & 1;
        const float* W = (m == 0) ? Wq : (m == 1) ? Wk : Wv;
        bf16* Wf       = (m == 0) ? Wqf : (m == 1) ? Wkf : Wvf;
        int slot = t & 15, rowb = t >> 4;
#pragma unroll
        for (int i = 0; i < 4; i++) {
            int rl_ = rowb + i * 16;           // local k-row 0..63
            float4 v = *(const float4*)(W + (size_t)(kh * 64 + rl_) * 2048 + cg * 64 + slot * 4);
            bf16x4 o; o[0]=(bf16)v.x; o[1]=(bf16)v.y; o[2]=(bf16)v.z; o[3]=(bf16)v.w;
            *(bf16x4*)(&pw[rl_ * 68 + slot * 4]) = o;   // tile [k 64][col 64] stride 68
        }
        __syncthreads();
        int ctl = wave;                        // local col-tile 0..3
#pragma unroll
        for (int kfl = 0; kfl < 2; kfl++) {
            bf16x8 w;
#pragma unroll
            for (int j = 0; j < 8; j++) w[j] = pw[(kfl * 32 + quad * 8 + j) * 68 + ctl * 16 + lrow];
            *(bf16x8*)(Wf + (size_t)((cg * 4 + ctl) * 4 + kh * 2 + kfl) * 512 + lane * 8) = w;
        }
    } else if (bid < 224) {
        // ---- Wo [2048][128]: block = 128 k-rows x 64-col half, PERMUTED ----
        int idx = bid - 192;
        int kb16 = idx >> 1, ch = idx & 1;
        int k0 = kb16 * 128;
        int slot = t & 15, rowb = t >> 4;
#pragma unroll
        for (int i = 0; i < 8; i++) {
            int r = rowb + i * 16;             // 0..127
            float4 v = *(const float4*)(Wo + (size_t)(k0 + r) * 128 + ch * 64 + slot * 4);
            bf16x4 o; o[0]=(bf16)v.x; o[1]=(bf16)v.y; o[2]=(bf16)v.z; o[3]=(bf16)v.w;
            *(bf16x4*)(&pw[r * 68 + slot * 4]) = o;     // tile [k 128][col 64] stride 68
        }
        __syncthreads();
        int ctl = wave;
        int ct = ch * 4 + ctl;
#pragma unroll
        for (int kfl = 0; kfl < 4; kfl++) {
            bf16x8 w;
            // PERMUTED k to match flash's O-concat A-frags:
            // elem j <- k = kfl*32 + (j>>2)*16 + quad*4 + (j&3)
#pragma unroll
            for (int j = 0; j < 8; j++)
                w[j] = pw[(kfl * 32 + ((j >> 2) << 4) + quad * 4 + (j & 3)) * 68 + ctl * 16 + lrow];
            *(bf16x8*)(Wof + (size_t)(ct * 64 + kb16 * 4 + kfl) * 512 + lane * 8) = w;
        }
    } else if (bid < 352) {
        // ---- x [4096][128] fp32 -> xf frags, 32 rows per block ----
        int idx = bid - 224, r0 = idx * 32;
        int slot = t & 31, rowb = t >> 5;
#pragma unroll
        for (int i = 0; i < 4; i++) {
            int r = rowb + i * 8;              // 0..31
            float4 v = *(const float4*)(x + (size_t)(r0 + r) * 128 + slot * 4);
            bf16x4 o; o[0]=(bf16)v.x; o[1]=(bf16)v.y; o[2]=(bf16)v.z; o[3]=(bf16)v.w;
            *(bf16x4*)(&pw[r * 136 + slot * 4]) = o;    // tile [row 32][col 128] stride 136
        }
        __syncthreads();
        int rtl = wave >> 1;                   // 2 row-tiles of 16
        int kf2 = (wave & 1) * 2;
#pragma unroll
        for (int kfl = 0; kfl < 2; kfl++) {
            int kf = kf2 + kfl;
            bf16x8 w = *(const bf16x8*)(&pw[(rtl * 16 + lrow) * 136 + kf * 32 + quad * 8]);
            *(bf16x8*)(xf + (size_t)((idx * 2 + rtl) * 4 + kf) * 512 + lane * 8) = w;
        }
    } else {
        int e = (bid - 352) * 256 + t;
        // log2-domain: exp2(-43.28) ~ 9e-14 ~ 0
        mbias[e] = mask[e] ? 0.0f : -43.2808512f;
    }
}

// ---------------------------------------------------------------------------
// Kernel A: Q/K/V projection — Z-FUSED (unchanged from R3).
// ---------------------------------------------------------------------------
__global__ __launch_bounds__(256) void qkv_proj(const bf16* __restrict__ xf,
                                                const float* __restrict__ bq,
                                                const float* __restrict__ bk,
                                                const float* __restrict__ bv,
                                                const bf16* __restrict__ Wqf,
                                                const bf16* __restrict__ Wkf,
                                                const bf16* __restrict__ Wvf,
                                                bf16* __restrict__ Qf,
                                                bf16* __restrict__ Kf,
                                                bf16* __restrict__ Vf) {
    __shared__ bf16 tile[64][72];

    int tid = threadIdx.x;
    int wave = tid >> 6, lane = tid & 63;
    int lrow = lane & 15, quad = lane >> 4;
    int r0b = blockIdx.x * 64;
    int c0 = blockIdx.y * 64;
    int cg4 = c0 >> 4;

    int rt = (r0b >> 4) + wave;
    bf16x8 a[4];
#pragma unroll
    for (int kf = 0; kf < 4; kf++)
        a[kf] = *(const bf16x8*)(xf + (size_t)(rt * 4 + kf) * 512 + lane * 8);

    int bb = r0b >> 11;
    int h  = c0 >> 7;
    int bhw = bb * 16 + h;
    int tile16 = (r0b & 2047) >> 4;
    int kbt = (r0b & 2047) >> 6;
    floatx4 zero4 = {0.f, 0.f, 0.f, 0.f};

#pragma unroll
    for (int z = 0; z < 3; z++) {
        const float* bias = (z == 0) ? bq : (z == 1) ? bk : bv;
        const bf16*  Wf   = (z == 0) ? Wqf : (z == 1) ? Wkf : Wvf;

        floatx4 acc[4] = {zero4, zero4, zero4, zero4};
#pragma unroll
        for (int kf = 0; kf < 4; kf++) {
#pragma unroll
            for (int nf = 0; nf < 4; nf++) {
                bf16x8 b = *(const bf16x8*)(Wf + (size_t)((cg4 + nf) * 4 + kf) * 512 + lane * 8);
                acc[nf] = MFMA32K(a[kf], b, acc[nf]);
            }
        }

#pragma unroll
        for (int nf = 0; nf < 4; nf++) {
            int col = nf * 16 + lrow;
            float bvv = bias[c0 + col];
#pragma unroll
            for (int r = 0; r < 4; r++) {
                int row = wave * 16 + quad * 4 + r;
                bf16 val = (bf16)(acc[nf][r] + bvv);
                if (z < 2) tile[row][col] = val;
                else       tile[col][row] = val;
            }
        }
        __syncthreads();

        if (z < 2) {
            bf16* dst = (z == 0) ? Qf : Kf;
            int s = wave;
            int kfbase = (c0 & 127) >> 5;
            size_t fbase = ((size_t)bhw * 128 + tile16 + s) * 4 + kfbase;
#pragma unroll
            for (int kfl = 0; kfl < 2; kfl++) {
                bf16x8 w = *(const bf16x8*)(&tile[s * 16 + lrow][kfl * 32 + quad * 8]);
                *(bf16x8*)(dst + (fbase + kfl) * 512 + lane * 8) = w;
            }
        } else {
            int nfl = wave;
            int nfbase = (c0 & 127) >> 4;
            size_t fbase = (((size_t)bhw * 32 + kbt) * 8 + (nfbase + nfl)) * 2;
#pragma unroll
            for (int g = 0; g < 2; g++) {
                bf16x4 a0 = *(const bf16x4*)(&tile[nfl * 16 + lrow][g * 32 + quad * 4]);
                bf16x4 a1 = *(const bf16x4*)(&tile[nfl * 16 + lrow][g * 32 + 16 + quad * 4]);
                bf16x8 w;
                w[0]=a0[0]; w[1]=a0[1]; w[2]=a0[2]; w[3]=a0[3];
                w[4]=a1[0]; w[5]=a1[1]; w[6]=a1[2]; w[7]=a1[3];
                *(bf16x8*)(Vf + (fbase + g) * 512 + lane * 8) = w;
            }
        }
        if (z < 2) __syncthreads();   // protect tile before next z overwrites
    }
}

// ---------------------------------------------------------------------------
// Kernel B: flash attention — NO-LDS / NO-BARRIER. R3/R4 evidence: the loop
// is pinned at 2 waves/SIMD and ~25% of the wall is stall that no vmcnt/
// prefetch variant removed; the remaining structural serializer is the
// per-iteration barrier + ds_read->MFMA chain. K's global addresses are
// byte-identical to what the DMA staged, and R3 proved a 16KB tile shared
// by 4 waves is absorbed by L1/L2 (V move: no FETCH increase). So: K comes
// from global with a one-phase register prefetch, V as in R4, mbias read
// directly from global (16-lane broadcast, L2-hot). Zero LDS, zero
// barriers, waves free-drift; the CU scheduler overlaps one wave's MFMA
// with another's loads. Same frag values, same summation order ->
// bit-identical output. L2 budget: 8 waves x 32KB/iter ~ 43 B/cyc/CU < 56;
// per-XCD K/V working set 4bh x 512KB = 2MB < 4MB L2 (XCD swizzle).
// ---------------------------------------------------------------------------
__global__ __launch_bounds__(256, 2) void flash_attn(const bf16* __restrict__ Qf,
                                                     const bf16* __restrict__ Kf,
                                                     const bf16* __restrict__ Vf,
                                                     const float* __restrict__ mbias,
                                                     const int* __restrict__ mask,
                                                     bf16* __restrict__ ctxf) {
    int tid = threadIdx.x;
    int wave = tid >> 6, lane = tid & 63;
    int lrow = lane & 15, quad = lane >> 4;
    // XCD swizzle: 512 blocks = 8 xcd * (4 bh * 16 qblk)
    int bid = blockIdx.x;
    int xcd = bid & 7, seq = bid >> 3;          // seq 0..63
    int bh  = xcd * 4 + (seq >> 4);             // 0..31
    int qblk = seq & 15;                        // 0..15
    int b  = bh >> 4;
    int q0 = qblk * 128 + wave * 32;

    const float* mbp = mbias + b * N_;
    const bf16* kbase = Kf + (size_t)bh * 262144 + lane * 8;
    const bf16* vbase = Vf + (size_t)bh * 262144 + lane * 8;

    // Q B-frags from Qf (coalesced 16B loads), held all loop
    bf16x8 qf[2][4];
#pragma unroll
    for (int u = 0; u < 2; u++)
#pragma unroll
        for (int kf = 0; kf < 4; kf++)
            qf[u][kf] = *(const bf16x8*)(Qf + (size_t)(((size_t)bh * 128 + (q0 >> 4) + u) * 4 + kf) * 512 + lane * 8);

    bf16x8 ones;
#pragma unroll
    for (int j = 0; j < 8; j++) ones[j] = (bf16)1.0f;

    floatx4 zero4 = {0.f, 0.f, 0.f, 0.f};
    floatx4 O[2][8];
#pragma unroll
    for (int u = 0; u < 2; u++)
#pragma unroll
        for (int nf = 0; nf < 8; nf++) O[u][nf] = zero4;
    floatx4 Oext[2] = {zero4, zero4};   // row sums l[q] via ones-MFMA

    const float scale = 0.12751742f;    // (1/sqrt(128)) * log2(e)

    // K frag (t, s, kf) lives at kbase + t*8192 + (s*4+kf)*512  (+lane*8)
    // ---- prologue: preload K s-tile (t=0, s=0) into registers ----
    bf16x8 kcur[4];
#pragma unroll
    for (int kf = 0; kf < 4; kf++)
        kcur[kf] = *(const bf16x8*)(kbase + kf * 512);

    for (int t = 0; t < 32; t++) {
        // ---- V(t) global->reg; consumed in PV below (latency hidden) ----
        const bf16* vsrc = vbase + (size_t)t * 8192;
        bf16x8 vreg[16];
#pragma unroll
        for (int f = 0; f < 16; f++)
            vreg[f] = *(const bf16x8*)(vsrc + f * 512);

        bf16x8 pfa[2], pfb[2];
#pragma unroll
        for (int s = 0; s < 4; s++) {
            // prefetch next K s-tile (clamped at the very end; value unused)
            int tn = (s == 3) ? ((t < 31) ? t + 1 : 31) : t;
            int sn = (s + 1) & 3;
            const bf16* knsrc = kbase + (size_t)tn * 8192 + sn * 2048;
            bf16x8 knxt[4];
#pragma unroll
            for (int kf = 0; kf < 4; kf++)
                knxt[kf] = *(const bf16x8*)(knsrc + kf * 512);

            // QK with the previously-loaded s-tile
            floatx4 S0 = zero4, S1 = zero4;
            __builtin_amdgcn_s_setprio(1);
#pragma unroll
            for (int kf = 0; kf < 4; kf++) {
                S0 = MFMA32K(kcur[kf], qf[0][kf], S0);
                S1 = MFMA32K(kcur[kf], qf[1][kf], S1);
            }
            __builtin_amdgcn_s_setprio(0);

            float4 mb4 = *(const float4*)(mbp + t * 64 + s * 16 + quad * 4);
            const float* mbr = (const float*)&mb4;
            int o = (s & 1) * 4;
#pragma unroll
            for (int r = 0; r < 4; r++) {
                float p0 = __builtin_amdgcn_exp2f(fmaf(S0[r], scale, mbr[r]));
                float p1 = __builtin_amdgcn_exp2f(fmaf(S1[r], scale, mbr[r]));
                if (s < 2) { pfa[0][o + r] = (bf16)p0; pfa[1][o + r] = (bf16)p1; }
                else       { pfb[0][o + r] = (bf16)p0; pfb[1][o + r] = (bf16)p1; }
            }
#pragma unroll
            for (int kf = 0; kf < 4; kf++) kcur[kf] = knxt[kf];

            // after s=1: PV + l-sum for g=0 (overlaps s=2,3 QK/exp2)
            if (s == 1) {
                __builtin_amdgcn_s_setprio(1);
                Oext[0] = MFMA32K(ones, pfa[0], Oext[0]);
                Oext[1] = MFMA32K(ones, pfa[1], Oext[1]);
#pragma unroll
                for (int nf = 0; nf < 8; nf++) {
                    O[0][nf] = MFMA32K(vreg[nf * 2], pfa[0], O[0][nf]);
                    O[1][nf] = MFMA32K(vreg[nf * 2], pfa[1], O[1][nf]);
                }
                __builtin_amdgcn_s_setprio(0);
            }
        }

        // ---- PV + l-sum for g=1 ----
        __builtin_amdgcn_s_setprio(1);
        Oext[0] = MFMA32K(ones, pfb[0], Oext[0]);
        Oext[1] = MFMA32K(ones, pfb[1], Oext[1]);
#pragma unroll
        for (int nf = 0; nf < 8; nf++) {
            O[0][nf] = MFMA32K(vreg[nf * 2 + 1], pfb[0], O[0][nf]);
            O[1][nf] = MFMA32K(vreg[nf * 2 + 1], pfb[1], O[1][nf]);
        }
        __builtin_amdgcn_s_setprio(0);
    }

    // ---- epilogue: normalize + DIRECT permuted-concat A-frag stores ----
    const int* mp = mask + b * N_;
    int h4 = (bh & 15) * 4;
    size_t qtb = (size_t)b * 128 + (q0 >> 4);
#pragma unroll
    for (int u = 0; u < 2; u++) {
        float lsum = Oext[u][0];
        int q = q0 + u * 16 + lrow;
        float rl = (mp[q] && lsum > 0.f) ? (1.0f / lsum) : 0.f;
#pragma unroll
        for (int g = 0; g < 4; g++) {
            bf16x8 w;
#pragma unroll
            for (int j = 0; j < 4; j++) {
                w[j]     = (bf16)(O[u][2 * g][j]     * rl);
                w[j + 4] = (bf16)(O[u][2 * g + 1][j] * rl);
            }
            *(bf16x8*)(ctxf + ((qtb + u) * 64 + h4 + g) * 512 + lane * 8) = w;
        }
    }
}

// ---------------------------------------------------------------------------
// Kernel C: out = ctx @ Wo + bo, fp32 out. SPLIT-K x2 (best measured form).
// ---------------------------------------------------------------------------
__global__ __launch_bounds__(128) void out_proj(const bf16* __restrict__ ctxf,
                                                const bf16* __restrict__ Wof,
                                                const float* __restrict__ bo,
                                                float* __restrict__ out) {
    __shared__ float red[512];         // wave1 partials: [nf2][r4][lane64]
    int tid = threadIdx.x;
    int wave = tid >> 6, lane = tid & 63;
    int lrow = lane & 15, quad = lane >> 4;
    int qt = blockIdx.x;               // 16-row tile
    int ct = blockIdx.y * 2;           // two 16-col tiles
    int r0 = qt * 16, c0 = ct * 16;

    floatx4 zero4 = {0.f, 0.f, 0.f, 0.f};
    floatx4 acc[2] = {zero4, zero4};
    const bf16* ap = ctxf + ((size_t)qt * 64 + wave * 32) * 512 + lane * 8;
    const bf16* b0 = Wof + ((size_t)ct * 64 + wave * 32) * 512 + lane * 8;
    const bf16* b1 = b0 + (size_t)64 * 512;
#pragma unroll 4
    for (int kf = 0; kf < 32; kf++) {
        bf16x8 a  = *(const bf16x8*)(ap + (size_t)kf * 512);
        bf16x8 w0 = *(const bf16x8*)(b0 + (size_t)kf * 512);
        bf16x8 w1 = *(const bf16x8*)(b1 + (size_t)kf * 512);
        acc[0] = MFMA32K(a, w0, acc[0]);
        acc[1] = MFMA32K(a, w1, acc[1]);
    }
    if (wave == 1) {
#pragma unroll
        for (int nf = 0; nf < 2; nf++)
#pragma unroll
            for (int r = 0; r < 4; r++)
                red[nf * 256 + r * 64 + lane] = acc[nf][r];
    }
    __syncthreads();
    if (wave == 0) {
#pragma unroll
        for (int nf = 0; nf < 2; nf++) {
            int col = c0 + nf * 16 + lrow;
            float bv = bo[col];
#pragma unroll
            for (int r = 0; r < 4; r++) {
                int m = r0 + quad * 4 + r;
                out[(size_t)m * 128 + col] = acc[nf][r] + red[nf * 256 + r * 64 + lane] + bv;
            }
        }
    }
}

// ---------------------------------------------------------------------------
extern "C" void kernel_launch(void* const* d_in, const int* in_sizes, int n_in,
                              void* d_out, int out_size, void* d_ws, size_t ws_size,
                              hipStream_t stream) {
    const float* x    = (const float*)d_in[0];
    const int*   mask = (const int*)d_in[1];
    const float* Wq   = (const float*)d_in[2];
    const float* bq   = (const float*)d_in[3];
    const float* Wk   = (const float*)d_in[4];
    const float* bk   = (const float*)d_in[5];
    const float* Wv   = (const float*)d_in[6];
    const float* bv   = (const float*)d_in[7];
    const float* Wo   = (const float*)d_in[8];
    const float* bo   = (const float*)d_in[9];
    float* out = (float*)d_out;

    char* ws = (char*)d_ws;
    size_t off = 0;
    bf16* Wqf = (bf16*)(ws + off); off += (size_t)262144 * 2;
    bf16* Wkf = (bf16*)(ws + off); off += (size_t)262144 * 2;
    bf16* Wvf = (bf16*)(ws + off); off += (size_t)262144 * 2;
    bf16* Wof = (bf16*)(ws + off); off += (size_t)262144 * 2;
    bf16* xf  = (bf16*)(ws + off); off += (size_t)524288 * 2;
    size_t qkv_elems = (size_t)BH_ * N_ * 128;           // 8.4M
    bf16* Qf  = (bf16*)(ws + off); off += qkv_elems * 2; // fragment-major
    bf16* Kf  = (bf16*)(ws + off); off += qkv_elems * 2;
    bf16* Vf  = (bf16*)(ws + off); off += qkv_elems * 2;
    bf16* ctxf = (bf16*)(ws + off); off += (size_t)M_ * ALL_ * 2;
    float* mbias = (float*)(ws + off); off += (size_t)B_ * N_ * 4;
    (void)ws_size; (void)in_sizes; (void)n_in; (void)out_size;

    prep_weights<<<368, 256, 0, stream>>>(x, Wq, Wk, Wv, Wo, mask,
                                          Wqf, Wkf, Wvf, Wof, xf, mbias);

    qkv_proj<<<dim3(64, 32), 256, 0, stream>>>(xf, bq, bk, bv, Wqf, Wkf, Wvf,
                                               Qf, Kf, Vf);

    flash_attn<<<512, 256, 0, stream>>>(Qf, Kf, Vf, mbias, mask, ctxf);

    out_proj<<<dim3(256, 4), 128, 0, stream>>>(ctxf, Wof, bo, out);
}

// Round 6
// 186.552 us; speedup vs baseline: 1.0174x; 1.0174x over previous
//
#include <hip/hip_runtime.h>
#include <hip/hip_bf16.h>

// Problem constants
#define B_   2
#define N_   2048
#define D_   128
#define H_   16
#define ALL_ 2048
#define M_   (B_*N_)    // 4096 total rows
#define BH_  (B_*H_)    // 32 (batch*heads)

typedef __bf16 bf16;
typedef __bf16 bf16x8 __attribute__((ext_vector_type(8)));
typedef __bf16 bf16x4 __attribute__((ext_vector_type(4)));
typedef float  floatx4 __attribute__((ext_vector_type(4)));

#define MFMA32K(a,b,c) __builtin_amdgcn_mfma_f32_16x16x32_bf16((a),(b),(c),0,0,0)

// async global->LDS DMA, 16B per lane (m97 pattern).
__device__ inline void load_lds16(const bf16* g, bf16* l) {
    __builtin_amdgcn_global_load_lds((const __attribute__((address_space(1))) void*)g,
                                     (__attribute__((address_space(3))) void*)l, 16, 0, 0);
}

#define WAITCNT_VM(n) ((0xF << 8) | (0x7 << 4) | (n))

// ---------------------------------------------------------------------------
// FRAGMENT-MAJOR LAYOUTS:
//  A/B-frag canonical (16x16x32): elem j of lane (lrow=lane&15,quad=lane>>4)
//    A[m=lrow][k=kf*32+quad*8+j]  /  B[k=kf*32+quad*8+j][n=lrow]
//  Wf  (Wq/Wk/Wv): [ct 128][kf 4][lane][8]  canonical
//  xf:  [rt 256][kf 4][lane][8]             canonical
//  Qf/Kf: [bh][t 128][kf 4][lane][8]        canonical
//  Vf:  [bh][kb 32][nf 8][g 2][lane][8]  PERMUTED k:
//        elem j = V[key=kb*64+(2g+(j>>2))*16+quad*4+(j&3)][d=nf*16+lrow]
//  ctxf: [qt 256][kf 64][lane][8]        PERMUTED k (same map over d):
//        elem j = ctx[q=qt*16+lrow][d' = (kf&3)*32+(j>>2)*16+quad*4+(j&3)]
//        (head = kf>>2) — written DIRECTLY from flash O accumulators.
//  Wof: [ct 8][kf 64][lane][8]           PERMUTED k to MATCH ctxf:
//        elem j = Wo[k = kf*32+(j>>2)*16+quad*4+(j&3)][col=ct*16+lrow]
//  MFMA contraction is invariant when A and B agree on the k-permutation.
//  mbias pre-scaled by log2(e) (exp2 path).
// ---------------------------------------------------------------------------

// ---------------------------------------------------------------------------
// Kernel T: prep — unchanged.
// ---------------------------------------------------------------------------
__global__ __launch_bounds__(256) void prep_weights(const float* __restrict__ x,
                                                    const float* __restrict__ Wq,
                                                    const float* __restrict__ Wk,
                                                    const float* __restrict__ Wv,
                                                    const float* __restrict__ Wo,
                                                    const int* __restrict__ mask,
                                                    bf16* __restrict__ Wqf,
                                                    bf16* __restrict__ Wkf,
                                                    bf16* __restrict__ Wvf,
                                                    bf16* __restrict__ Wof,
                                                    bf16* __restrict__ xf,
                                                    float* __restrict__ mbias) {
    __shared__ bf16 pw[16896];
    int bid = blockIdx.x, t = threadIdx.x;
    int lane = t & 63, wave = t >> 6;
    int lrow = lane & 15, quad = lane >> 4;

    if (bid < 192) {
        // ---- Wq/Wk/Wv [128][2048]: block = 64 k-rows (half) x 64 cols ----
        int m = bid / 64, rest = bid % 64;
        int cg = rest >> 1, kh = rest & 1;
        const float* W = (m == 0) ? Wq : (m == 1) ? Wk : Wv;
        bf16* Wf       = (m == 0) ? Wqf : (m == 1) ? Wkf : Wvf;
        int slot = t & 15, rowb = t >> 4;
#pragma unroll
        for (int i = 0; i < 4; i++) {
            int rl_ = rowb + i * 16;           // local k-row 0..63
            float4 v = *(const float4*)(W + (size_t)(kh * 64 + rl_) * 2048 + cg * 64 + slot * 4);
            bf16x4 o; o[0]=(bf16)v.x; o[1]=(bf16)v.y; o[2]=(bf16)v.z; o[3]=(bf16)v.w;
            *(bf16x4*)(&pw[rl_ * 68 + slot * 4]) = o;   // tile [k 64][col 64] stride 68
        }
        __syncthreads();
        int ctl = wave;                        // local col-tile 0..3
#pragma unroll
        for (int kfl = 0; kfl < 2; kfl++) {
            bf16x8 w;
#pragma unroll
            for (int j = 0; j < 8; j++) w[j] = pw[(kfl * 32 + quad * 8 + j) * 68 + ctl * 16 + lrow];
            *(bf16x8*)(Wf + (size_t)((cg * 4 + ctl) * 4 + kh * 2 + kfl) * 512 + lane * 8) = w;
        }
    } else if (bid < 224) {
        // ---- Wo [2048][128]: block = 128 k-rows x 64-col half, PERMUTED ----
        int idx = bid - 192;
        int kb16 = idx >> 1, ch = idx & 1;
        int k0 = kb16 * 128;
        int slot = t & 15, rowb = t >> 4;
#pragma unroll
        for (int i = 0; i < 8; i++) {
            int r = rowb + i * 16;             // 0..127
            float4 v = *(const float4*)(Wo + (size_t)(k0 + r) * 128 + ch * 64 + slot * 4);
            bf16x4 o; o[0]=(bf16)v.x; o[1]=(bf16)v.y; o[2]=(bf16)v.z; o[3]=(bf16)v.w;
            *(bf16x4*)(&pw[r * 68 + slot * 4]) = o;     // tile [k 128][col 64] stride 68
        }
        __syncthreads();
        int ctl = wave;
        int ct = ch * 4 + ctl;
#pragma unroll
        for (int kfl = 0; kfl < 4; kfl++) {
            bf16x8 w;
            // PERMUTED k to match flash's O-concat A-frags:
            // elem j <- k = kfl*32 + (j>>2)*16 + quad*4 + (j&3)
#pragma unroll
            for (int j = 0; j < 8; j++)
                w[j] = pw[(kfl * 32 + ((j >> 2) << 4) + quad * 4 + (j & 3)) * 68 + ctl * 16 + lrow];
            *(bf16x8*)(Wof + (size_t)(ct * 64 + kb16 * 4 + kfl) * 512 + lane * 8) = w;
        }
    } else if (bid < 352) {
        // ---- x [4096][128] fp32 -> xf frags, 32 rows per block ----
        int idx = bid - 224, r0 = idx * 32;
        int slot = t & 31, rowb = t >> 5;
#pragma unroll
        for (int i = 0; i < 4; i++) {
            int r = rowb + i * 8;              // 0..31
            float4 v = *(const float4*)(x + (size_t)(r0 + r) * 128 + slot * 4);
            bf16x4 o; o[0]=(bf16)v.x; o[1]=(bf16)v.y; o[2]=(bf16)v.z; o[3]=(bf16)v.w;
            *(bf16x4*)(&pw[r * 136 + slot * 4]) = o;    // tile [row 32][col 128] stride 136
        }
        __syncthreads();
        int rtl = wave >> 1;                   // 2 row-tiles of 16
        int kf2 = (wave & 1) * 2;
#pragma unroll
        for (int kfl = 0; kfl < 2; kfl++) {
            int kf = kf2 + kfl;
            bf16x8 w = *(const bf16x8*)(&pw[(rtl * 16 + lrow) * 136 + kf * 32 + quad * 8]);
            *(bf16x8*)(xf + (size_t)((idx * 2 + rtl) * 4 + kf) * 512 + lane * 8) = w;
        }
    } else {
        int e = (bid - 352) * 256 + t;
        // log2-domain: exp2(-43.28) ~ 9e-14 ~ 0
        mbias[e] = mask[e] ? 0.0f : -43.2808512f;
    }
}

// ---------------------------------------------------------------------------
// Kernel A: Q/K/V projection — Z-FUSED (unchanged from R3).
// ---------------------------------------------------------------------------
__global__ __launch_bounds__(256) void qkv_proj(const bf16* __restrict__ xf,
                                                const float* __restrict__ bq,
                                                const float* __restrict__ bk,
                                                const float* __restrict__ bv,
                                                const bf16* __restrict__ Wqf,
                                                const bf16* __restrict__ Wkf,
                                                const bf16* __restrict__ Wvf,
                                                bf16* __restrict__ Qf,
                                                bf16* __restrict__ Kf,
                                                bf16* __restrict__ Vf) {
    __shared__ bf16 tile[64][72];

    int tid = threadIdx.x;
    int wave = tid >> 6, lane = tid & 63;
    int lrow = lane & 15, quad = lane >> 4;
    int r0b = blockIdx.x * 64;
    int c0 = blockIdx.y * 64;
    int cg4 = c0 >> 4;

    int rt = (r0b >> 4) + wave;
    bf16x8 a[4];
#pragma unroll
    for (int kf = 0; kf < 4; kf++)
        a[kf] = *(const bf16x8*)(xf + (size_t)(rt * 4 + kf) * 512 + lane * 8);

    int bb = r0b >> 11;
    int h  = c0 >> 7;
    int bhw = bb * 16 + h;
    int tile16 = (r0b & 2047) >> 4;
    int kbt = (r0b & 2047) >> 6;
    floatx4 zero4 = {0.f, 0.f, 0.f, 0.f};

#pragma unroll
    for (int z = 0; z < 3; z++) {
        const float* bias = (z == 0) ? bq : (z == 1) ? bk : bv;
        const bf16*  Wf   = (z == 0) ? Wqf : (z == 1) ? Wkf : Wvf;

        floatx4 acc[4] = {zero4, zero4, zero4, zero4};
#pragma unroll
        for (int kf = 0; kf < 4; kf++) {
#pragma unroll
            for (int nf = 0; nf < 4; nf++) {
                bf16x8 b = *(const bf16x8*)(Wf + (size_t)((cg4 + nf) * 4 + kf) * 512 + lane * 8);
                acc[nf] = MFMA32K(a[kf], b, acc[nf]);
            }
        }

#pragma unroll
        for (int nf = 0; nf < 4; nf++) {
            int col = nf * 16 + lrow;
            float bvv = bias[c0 + col];
#pragma unroll
            for (int r = 0; r < 4; r++) {
                int row = wave * 16 + quad * 4 + r;
                bf16 val = (bf16)(acc[nf][r] + bvv);
                if (z < 2) tile[row][col] = val;
                else       tile[col][row] = val;
            }
        }
        __syncthreads();

        if (z < 2) {
            bf16* dst = (z == 0) ? Qf : Kf;
            int s = wave;
            int kfbase = (c0 & 127) >> 5;
            size_t fbase = ((size_t)bhw * 128 + tile16 + s) * 4 + kfbase;
#pragma unroll
            for (int kfl = 0; kfl < 2; kfl++) {
                bf16x8 w = *(const bf16x8*)(&tile[s * 16 + lrow][kfl * 32 + quad * 8]);
                *(bf16x8*)(dst + (fbase + kfl) * 512 + lane * 8) = w;
            }
        } else {
            int nfl = wave;
            int nfbase = (c0 & 127) >> 4;
            size_t fbase = (((size_t)bhw * 32 + kbt) * 8 + (nfbase + nfl)) * 2;
#pragma unroll
            for (int g = 0; g < 2; g++) {
                bf16x4 a0 = *(const bf16x4*)(&tile[nfl * 16 + lrow][g * 32 + quad * 4]);
                bf16x4 a1 = *(const bf16x4*)(&tile[nfl * 16 + lrow][g * 32 + 16 + quad * 4]);
                bf16x8 w;
                w[0]=a0[0]; w[1]=a0[1]; w[2]=a0[2]; w[3]=a0[3];
                w[4]=a1[0]; w[5]=a1[1]; w[6]=a1[2]; w[7]=a1[3];
                *(bf16x8*)(Vf + (fbase + g) * 512 + lane * 8) = w;
            }
        }
        if (z < 2) __syncthreads();   // protect tile before next z overwrites
    }
}

// ---------------------------------------------------------------------------
// Kernel B: flash attention — 16 q-rows/wave, 8-wave blocks (512 thr), for
// 4 waves/SIMD. R0-R5 evidence: 2 waves/SIMD cannot overlap the 4-stage
// chain (V-load -> QK -> exp2 -> PV); all schedule variants landed 82-85 µs.
// Occupancy is VGPR-step-locked (m69: halves at 64/128/256): 32q/wave needs
// ~150 regs -> 8 waves/CU. Halving per-wave state (O 64->32 regs) fits the
// 128-reg step: __launch_bounds__(512,4) -> 16 waves/CU. K stays in LDS
// (R5 showed K-from-global overloads VMEM); V from global (R3-proven,
// L1-shared); per-CU K-LDS traffic doubles (3456 cyc) but the binder
// becomes VMEM ~4096 cyc < the old 6200 wall. Same key order, same MFMA
// shapes, same summation order -> bit-identical output.
// ---------------------------------------------------------------------------
__global__ __launch_bounds__(512, 4) void flash_attn(const bf16* __restrict__ Qf,
                                                     const bf16* __restrict__ Kf,
                                                     const bf16* __restrict__ Vf,
                                                     const float* __restrict__ mbias,
                                                     const int* __restrict__ mask,
                                                     bf16* __restrict__ ctxf) {
    // K double-buffer: 2 x 8192 elems (16 KB each)
    __shared__ bf16 sm[16384];
    __shared__ float mbL[2048];    // mbias row (8 KB). LDS total 40960 B.

    int tid = threadIdx.x;
    int wave = tid >> 6, lane = tid & 63;
    int lrow = lane & 15, quad = lane >> 4;
    // XCD swizzle: 512 blocks = 8 xcd * (4 bh * 16 qblk)
    int bid = blockIdx.x;
    int xcd = bid & 7, seq = bid >> 3;          // seq 0..63
    int bh  = xcd * 4 + (seq >> 4);             // 0..31
    int qblk = seq & 15;                        // 0..15
    int b  = bh >> 4;
    int q0 = qblk * 128 + wave * 16;            // 16 q-rows per wave

    const float* mbp = mbias + b * N_;
    const bf16* kbase = Kf + (size_t)bh * 262144;
    const bf16* vbase = Vf + (size_t)bh * 262144 + lane * 8;

    // Q B-frags (one 16-row tile), held all loop: 16 VGPR
    bf16x8 qf[4];
#pragma unroll
    for (int kf = 0; kf < 4; kf++)
        qf[kf] = *(const bf16x8*)(Qf + (size_t)(((size_t)bh * 128 + (q0 >> 4)) * 4 + kf) * 512 + lane * 8);

    bf16x8 ones;
#pragma unroll
    for (int j = 0; j < 8; j++) ones[j] = (bf16)1.0f;

    floatx4 zero4 = {0.f, 0.f, 0.f, 0.f};
    floatx4 O[8];                       // O^T[d=nf*16+..][q 16]: 32 regs
#pragma unroll
    for (int nf = 0; nf < 8; nf++) O[nf] = zero4;
    floatx4 Oext = zero4;               // row sums l[q] via ones-MFMA

    const float scale = 0.12751742f;    // (1/sqrt(128)) * log2(e)

    // ---- prologue: K(0) DMA (2 segs/wave) + mbias (1 seg/wave) ----
#pragma unroll
    for (int i = 0; i < 2; i++) {
        int seg = wave * 2 + i;                // 0..15, 1KB each
        load_lds16(kbase + seg * 512 + lane * 8, &sm[seg * 512]);
    }
    load_lds16((const bf16*)(mbp + wave * 256) + lane * 8, (bf16*)(mbL + wave * 256));

    for (int t = 0; t < 32; t++) {
        int cur = (t & 1) << 13;               // elems: 0 or 8192

        // wait my K-DMA(t) (+mbias at t==0); V(t-1) already drained by use
        __builtin_amdgcn_s_waitcnt(WAITCNT_VM(0));
        __builtin_amdgcn_s_barrier();

        // prefetch K(t+1) into the other buffer
        if (t < 31) {
            int nxt = cur ^ 8192;
            const bf16* ksrc = kbase + (size_t)(t + 1) * 8192;
#pragma unroll
            for (int i = 0; i < 2; i++) {
                int seg = wave * 2 + i;
                load_lds16(ksrc + seg * 512 + lane * 8, &sm[nxt + seg * 512]);
            }
        }

        // V g=0 frags global->reg (L1-shared); consumed after phase A
        const bf16* vsrc = vbase + (size_t)t * 8192;
        bf16x8 v0[8];
#pragma unroll
        for (int nf = 0; nf < 8; nf++)
            v0[nf] = *(const bf16x8*)(vsrc + (nf * 2) * 512);

        // ---- phase A: s=0,1 QK + exp2 -> pfa (keys t*64 .. +31) ----
        bf16x8 pfa;
#pragma unroll
        for (int s = 0; s < 2; s++) {
            floatx4 S = zero4;
            __builtin_amdgcn_s_setprio(1);
#pragma unroll
            for (int kf = 0; kf < 4; kf++) {
                bf16x8 kfr = *(const bf16x8*)(&sm[cur + ((s * 4 + kf) * 64 + lane) * 8]);
                S = MFMA32K(kfr, qf[kf], S);
            }
            __builtin_amdgcn_s_setprio(0);
            float4 mb4 = *(const float4*)(mbL + t * 64 + s * 16 + quad * 4);
            const float* mbr = (const float*)&mb4;
            int o = s * 4;
#pragma unroll
            for (int r = 0; r < 4; r++)
                pfa[o + r] = (bf16)__builtin_amdgcn_exp2f(fmaf(S[r], scale, mbr[r]));
        }

        // ---- PV + l-sum g=0 ----
        __builtin_amdgcn_s_setprio(1);
        Oext = MFMA32K(ones, pfa, Oext);
#pragma unroll
        for (int nf = 0; nf < 8; nf++)
            O[nf] = MFMA32K(v0[nf], pfa, O[nf]);
        __builtin_amdgcn_s_setprio(0);

        // V g=1 frags (latency hidden under phase B)
        bf16x8 v1[8];
#pragma unroll
        for (int nf = 0; nf < 8; nf++)
            v1[nf] = *(const bf16x8*)(vsrc + (nf * 2 + 1) * 512);

        // ---- phase B: s=2,3 QK + exp2 -> pfb (keys t*64+32 .. +63) ----
        bf16x8 pfb;
#pragma unroll
        for (int s = 2; s < 4; s++) {
            floatx4 S = zero4;
            __builtin_amdgcn_s_setprio(1);
#pragma unroll
            for (int kf = 0; kf < 4; kf++) {
                bf16x8 kfr = *(const bf16x8*)(&sm[cur + ((s * 4 + kf) * 64 + lane) * 8]);
                S = MFMA32K(kfr, qf[kf], S);
            }
            __builtin_amdgcn_s_setprio(0);
            float4 mb4 = *(const float4*)(mbL + t * 64 + s * 16 + quad * 4);
            const float* mbr = (const float*)&mb4;
            int o = (s - 2) * 4;
#pragma unroll
            for (int r = 0; r < 4; r++)
                pfb[o + r] = (bf16)__builtin_amdgcn_exp2f(fmaf(S[r], scale, mbr[r]));
        }

        // ---- PV + l-sum g=1 ----
        __builtin_amdgcn_s_setprio(1);
        Oext = MFMA32K(ones, pfb, Oext);
#pragma unroll
        for (int nf = 0; nf < 8; nf++)
            O[nf] = MFMA32K(v1[nf], pfb, O[nf]);
        __builtin_amdgcn_s_setprio(0);
        // no end-of-iter barrier: next iter's vmcnt(0)+barrier protects buf
    }

    // ---- epilogue: normalize + DIRECT permuted-concat A-frag stores ----
    const int* mp = mask + b * N_;
    int h4 = (bh & 15) * 4;
    size_t qtb = (size_t)b * 128 + (q0 >> 4);
    float lsum = Oext[0];
    int q = q0 + lrow;
    float rl = (mp[q] && lsum > 0.f) ? (1.0f / lsum) : 0.f;
#pragma unroll
    for (int g = 0; g < 4; g++) {
        bf16x8 w;
#pragma unroll
        for (int j = 0; j < 4; j++) {
            w[j]     = (bf16)(O[2 * g][j]     * rl);
            w[j + 4] = (bf16)(O[2 * g + 1][j] * rl);
        }
        *(bf16x8*)(ctxf + (qtb * 64 + h4 + g) * 512 + lane * 8) = w;
    }
}

// ---------------------------------------------------------------------------
// Kernel C: out = ctx @ Wo + bo, fp32 out. SPLIT-K x2 (best measured form).
// ---------------------------------------------------------------------------
__global__ __launch_bounds__(128) void out_proj(const bf16* __restrict__ ctxf,
                                                const bf16* __restrict__ Wof,
                                                const float* __restrict__ bo,
                                                float* __restrict__ out) {
    __shared__ float red[512];         // wave1 partials: [nf2][r4][lane64]
    int tid = threadIdx.x;
    int wave = tid >> 6, lane = tid & 63;
    int lrow = lane & 15, quad = lane >> 4;
    int qt = blockIdx.x;               // 16-row tile
    int ct = blockIdx.y * 2;           // two 16-col tiles
    int r0 = qt * 16, c0 = ct * 16;

    floatx4 zero4 = {0.f, 0.f, 0.f, 0.f};
    floatx4 acc[2] = {zero4, zero4};
    const bf16* ap = ctxf + ((size_t)qt * 64 + wave * 32) * 512 + lane * 8;
    const bf16* b0 = Wof + ((size_t)ct * 64 + wave * 32) * 512 + lane * 8;
    const bf16* b1 = b0 + (size_t)64 * 512;
#pragma unroll 4
    for (int kf = 0; kf < 32; kf++) {
        bf16x8 a  = *(const bf16x8*)(ap + (size_t)kf * 512);
        bf16x8 w0 = *(const bf16x8*)(b0 + (size_t)kf * 512);
        bf16x8 w1 = *(const bf16x8*)(b1 + (size_t)kf * 512);
        acc[0] = MFMA32K(a, w0, acc[0]);
        acc[1] = MFMA32K(a, w1, acc[1]);
    }
    if (wave == 1) {
#pragma unroll
        for (int nf = 0; nf < 2; nf++)
#pragma unroll
            for (int r = 0; r < 4; r++)
                red[nf * 256 + r * 64 + lane] = acc[nf][r];
    }
    __syncthreads();
    if (wave == 0) {
#pragma unroll
        for (int nf = 0; nf < 2; nf++) {
            int col = c0 + nf * 16 + lrow;
            float bv = bo[col];
#pragma unroll
            for (int r = 0; r < 4; r++) {
                int m = r0 + quad * 4 + r;
                out[(size_t)m * 128 + col] = acc[nf][r] + red[nf * 256 + r * 64 + lane] + bv;
            }
        }
    }
}

// ---------------------------------------------------------------------------
extern "C" void kernel_launch(void* const* d_in, const int* in_sizes, int n_in,
                              void* d_out, int out_size, void* d_ws, size_t ws_size,
                              hipStream_t stream) {
    const float* x    = (const float*)d_in[0];
    const int*   mask = (const int*)d_in[1];
    const float* Wq   = (const float*)d_in[2];
    const float* bq   = (const float*)d_in[3];
    const float* Wk   = (const float*)d_in[4];
    const float* bk   = (const float*)d_in[5];
    const float* Wv   = (const float*)d_in[6];
    const float* bv   = (const float*)d_in[7];
    const float* Wo   = (const float*)d_in[8];
    const float* bo   = (const float*)d_in[9];
    float* out = (float*)d_out;

    char* ws = (char*)d_ws;
    size_t off = 0;
    bf16* Wqf = (bf16*)(ws + off); off += (size_t)262144 * 2;
    bf16* Wkf = (bf16*)(ws + off); off += (size_t)262144 * 2;
    bf16* Wvf = (bf16*)(ws + off); off += (size_t)262144 * 2;
    bf16* Wof = (bf16*)(ws + off); off += (size_t)262144 * 2;
    bf16* xf  = (bf16*)(ws + off); off += (size_t)524288 * 2;
    size_t qkv_elems = (size_t)BH_ * N_ * 128;           // 8.4M
    bf16* Qf  = (bf16*)(ws + off); off += qkv_elems * 2; // fragment-major
    bf16* Kf  = (bf16*)(ws + off); off += qkv_elems * 2;
    bf16* Vf  = (bf16*)(ws + off); off += qkv_elems * 2;
    bf16* ctxf = (bf16*)(ws + off); off += (size_t)M_ * ALL_ * 2;
    float* mbias = (float*)(ws + off); off += (size_t)B_ * N_ * 4;
    (void)ws_size; (void)in_sizes; (void)n_in; (void)out_size;

    prep_weights<<<368, 256, 0, stream>>>(x, Wq, Wk, Wv, Wo, mask,
                                          Wqf, Wkf, Wvf, Wof, xf, mbias);

    qkv_proj<<<dim3(64, 32), 256, 0, stream>>>(xf, bq, bk, bv, Wqf, Wkf, Wvf,
                                               Qf, Kf, Vf);

    flash_attn<<<512, 512, 0, stream>>>(Qf, Kf, Vf, mbias, mask, ctxf);

    out_proj<<<dim3(256, 4), 128, 0, stream>>>(ctxf, Wof, bo, out);
}

// Round 7
// 176.365 us; speedup vs baseline: 1.0762x; 1.0578x over previous
//
#include <hip/hip_runtime.h>
#include <hip/hip_bf16.h>

// Problem constants
#define B_   2
#define N_   2048
#define D_   128
#define H_   16
#define ALL_ 2048
#define M_   (B_*N_)    // 4096 total rows
#define BH_  (B_*H_)    // 32 (batch*heads)

typedef __bf16 bf16;
typedef __bf16 bf16x8 __attribute__((ext_vector_type(8)));
typedef __bf16 bf16x4 __attribute__((ext_vector_type(4)));
typedef float  floatx4 __attribute__((ext_vector_type(4)));

#define MFMA32K(a,b,c) __builtin_amdgcn_mfma_f32_16x16x32_bf16((a),(b),(c),0,0,0)

// async global->LDS DMA, 16B per lane (m97 pattern).
__device__ inline void load_lds16(const bf16* g, bf16* l) {
    __builtin_amdgcn_global_load_lds((const __attribute__((address_space(1))) void*)g,
                                     (__attribute__((address_space(3))) void*)l, 16, 0, 0);
}

#define WAITCNT_VM(n) ((0xF << 8) | (0x7 << 4) | (n))

// ---------------------------------------------------------------------------
// FRAGMENT-MAJOR LAYOUTS:
//  A/B-frag canonical (16x16x32): elem j of lane (lrow=lane&15,quad=lane>>4)
//    A[m=lrow][k=kf*32+quad*8+j]  /  B[k=kf*32+quad*8+j][n=lrow]
//  Wf  (Wq/Wk/Wv): [ct 128][kf 4][lane][8]  canonical
//  xf:  [rt 256][kf 4][lane][8]             canonical
//  Qf/Kf: [bh][t 128][kf 4][lane][8]        canonical
//  Vf:  [bh][kb 32][nf 8][g 2][lane][8]  PERMUTED k:
//        elem j = V[key=kb*64+(2g+(j>>2))*16+quad*4+(j&3)][d=nf*16+lrow]
//  ctxf: [qt 256][kf 64][lane][8]        PERMUTED k (same map over d):
//        elem j = ctx[q=qt*16+lrow][d' = (kf&3)*32+(j>>2)*16+quad*4+(j&3)]
//        (head = kf>>2) — written DIRECTLY from flash O accumulators.
//  Wof: [ct 8][kf 64][lane][8]           PERMUTED k to MATCH ctxf:
//        elem j = Wo[k = kf*32+(j>>2)*16+quad*4+(j&3)][col=ct*16+lrow]
//  MFMA contraction is invariant when A and B agree on the k-permutation.
//  mbias pre-scaled by log2(e) (exp2 path).
// ---------------------------------------------------------------------------

// ---------------------------------------------------------------------------
// Kernel T: prep — unchanged.
// ---------------------------------------------------------------------------
__global__ __launch_bounds__(256) void prep_weights(const float* __restrict__ x,
                                                    const float* __restrict__ Wq,
                                                    const float* __restrict__ Wk,
                                                    const float* __restrict__ Wv,
                                                    const float* __restrict__ Wo,
                                                    const int* __restrict__ mask,
                                                    bf16* __restrict__ Wqf,
                                                    bf16* __restrict__ Wkf,
                                                    bf16* __restrict__ Wvf,
                                                    bf16* __restrict__ Wof,
                                                    bf16* __restrict__ xf,
                                                    float* __restrict__ mbias) {
    __shared__ bf16 pw[16896];
    int bid = blockIdx.x, t = threadIdx.x;
    int lane = t & 63, wave = t >> 6;
    int lrow = lane & 15, quad = lane >> 4;

    if (bid < 192) {
        // ---- Wq/Wk/Wv [128][2048]: block = 64 k-rows (half) x 64 cols ----
        int m = bid / 64, rest = bid % 64;
        int cg = rest >> 1, kh = rest & 1;
        const float* W = (m == 0) ? Wq : (m == 1) ? Wk : Wv;
        bf16* Wf       = (m == 0) ? Wqf : (m == 1) ? Wkf : Wvf;
        int slot = t & 15, rowb = t >> 4;
#pragma unroll
        for (int i = 0; i < 4; i++) {
            int rl_ = rowb + i * 16;           // local k-row 0..63
            float4 v = *(const float4*)(W + (size_t)(kh * 64 + rl_) * 2048 + cg * 64 + slot * 4);
            bf16x4 o; o[0]=(bf16)v.x; o[1]=(bf16)v.y; o[2]=(bf16)v.z; o[3]=(bf16)v.w;
            *(bf16x4*)(&pw[rl_ * 68 + slot * 4]) = o;   // tile [k 64][col 64] stride 68
        }
        __syncthreads();
        int ctl = wave;                        // local col-tile 0..3
#pragma unroll
        for (int kfl = 0; kfl < 2; kfl++) {
            bf16x8 w;
#pragma unroll
            for (int j = 0; j < 8; j++) w[j] = pw[(kfl * 32 + quad * 8 + j) * 68 + ctl * 16 + lrow];
            *(bf16x8*)(Wf + (size_t)((cg * 4 + ctl) * 4 + kh * 2 + kfl) * 512 + lane * 8) = w;
        }
    } else if (bid < 224) {
        // ---- Wo [2048][128]: block = 128 k-rows x 64-col half, PERMUTED ----
        int idx = bid - 192;
        int kb16 = idx >> 1, ch = idx & 1;
        int k0 = kb16 * 128;
        int slot = t & 15, rowb = t >> 4;
#pragma unroll
        for (int i = 0; i < 8; i++) {
            int r = rowb + i * 16;             // 0..127
            float4 v = *(const float4*)(Wo + (size_t)(k0 + r) * 128 + ch * 64 + slot * 4);
            bf16x4 o; o[0]=(bf16)v.x; o[1]=(bf16)v.y; o[2]=(bf16)v.z; o[3]=(bf16)v.w;
            *(bf16x4*)(&pw[r * 68 + slot * 4]) = o;     // tile [k 128][col 64] stride 68
        }
        __syncthreads();
        int ctl = wave;
        int ct = ch * 4 + ctl;
#pragma unroll
        for (int kfl = 0; kfl < 4; kfl++) {
            bf16x8 w;
            // PERMUTED k to match flash's O-concat A-frags:
            // elem j <- k = kfl*32 + (j>>2)*16 + quad*4 + (j&3)
#pragma unroll
            for (int j = 0; j < 8; j++)
                w[j] = pw[(kfl * 32 + ((j >> 2) << 4) + quad * 4 + (j & 3)) * 68 + ctl * 16 + lrow];
            *(bf16x8*)(Wof + (size_t)(ct * 64 + kb16 * 4 + kfl) * 512 + lane * 8) = w;
        }
    } else if (bid < 352) {
        // ---- x [4096][128] fp32 -> xf frags, 32 rows per block ----
        int idx = bid - 224, r0 = idx * 32;
        int slot = t & 31, rowb = t >> 5;
#pragma unroll
        for (int i = 0; i < 4; i++) {
            int r = rowb + i * 8;              // 0..31
            float4 v = *(const float4*)(x + (size_t)(r0 + r) * 128 + slot * 4);
            bf16x4 o; o[0]=(bf16)v.x; o[1]=(bf16)v.y; o[2]=(bf16)v.z; o[3]=(bf16)v.w;
            *(bf16x4*)(&pw[r * 136 + slot * 4]) = o;    // tile [row 32][col 128] stride 136
        }
        __syncthreads();
        int rtl = wave >> 1;                   // 2 row-tiles of 16
        int kf2 = (wave & 1) * 2;
#pragma unroll
        for (int kfl = 0; kfl < 2; kfl++) {
            int kf = kf2 + kfl;
            bf16x8 w = *(const bf16x8*)(&pw[(rtl * 16 + lrow) * 136 + kf * 32 + quad * 8]);
            *(bf16x8*)(xf + (size_t)((idx * 2 + rtl) * 4 + kf) * 512 + lane * 8) = w;
        }
    } else {
        int e = (bid - 352) * 256 + t;
        // log2-domain: exp2(-43.28) ~ 9e-14 ~ 0
        mbias[e] = mask[e] ? 0.0f : -43.2808512f;
    }
}

// ---------------------------------------------------------------------------
// Kernel A: Q/K/V projection — Z-FUSED (unchanged from R3).
// ---------------------------------------------------------------------------
__global__ __launch_bounds__(256) void qkv_proj(const bf16* __restrict__ xf,
                                                const float* __restrict__ bq,
                                                const float* __restrict__ bk,
                                                const float* __restrict__ bv,
                                                const bf16* __restrict__ Wqf,
                                                const bf16* __restrict__ Wkf,
                                                const bf16* __restrict__ Wvf,
                                                bf16* __restrict__ Qf,
                                                bf16* __restrict__ Kf,
                                                bf16* __restrict__ Vf) {
    __shared__ bf16 tile[64][72];

    int tid = threadIdx.x;
    int wave = tid >> 6, lane = tid & 63;
    int lrow = lane & 15, quad = lane >> 4;
    int r0b = blockIdx.x * 64;
    int c0 = blockIdx.y * 64;
    int cg4 = c0 >> 4;

    int rt = (r0b >> 4) + wave;
    bf16x8 a[4];
#pragma unroll
    for (int kf = 0; kf < 4; kf++)
        a[kf] = *(const bf16x8*)(xf + (size_t)(rt * 4 + kf) * 512 + lane * 8);

    int bb = r0b >> 11;
    int h  = c0 >> 7;
    int bhw = bb * 16 + h;
    int tile16 = (r0b & 2047) >> 4;
    int kbt = (r0b & 2047) >> 6;
    floatx4 zero4 = {0.f, 0.f, 0.f, 0.f};

#pragma unroll
    for (int z = 0; z < 3; z++) {
        const float* bias = (z == 0) ? bq : (z == 1) ? bk : bv;
        const bf16*  Wf   = (z == 0) ? Wqf : (z == 1) ? Wkf : Wvf;

        floatx4 acc[4] = {zero4, zero4, zero4, zero4};
#pragma unroll
        for (int kf = 0; kf < 4; kf++) {
#pragma unroll
            for (int nf = 0; nf < 4; nf++) {
                bf16x8 b = *(const bf16x8*)(Wf + (size_t)((cg4 + nf) * 4 + kf) * 512 + lane * 8);
                acc[nf] = MFMA32K(a[kf], b, acc[nf]);
            }
        }

#pragma unroll
        for (int nf = 0; nf < 4; nf++) {
            int col = nf * 16 + lrow;
            float bvv = bias[c0 + col];
#pragma unroll
            for (int r = 0; r < 4; r++) {
                int row = wave * 16 + quad * 4 + r;
                bf16 val = (bf16)(acc[nf][r] + bvv);
                if (z < 2) tile[row][col] = val;
                else       tile[col][row] = val;
            }
        }
        __syncthreads();

        if (z < 2) {
            bf16* dst = (z == 0) ? Qf : Kf;
            int s = wave;
            int kfbase = (c0 & 127) >> 5;
            size_t fbase = ((size_t)bhw * 128 + tile16 + s) * 4 + kfbase;
#pragma unroll
            for (int kfl = 0; kfl < 2; kfl++) {
                bf16x8 w = *(const bf16x8*)(&tile[s * 16 + lrow][kfl * 32 + quad * 8]);
                *(bf16x8*)(dst + (fbase + kfl) * 512 + lane * 8) = w;
            }
        } else {
            int nfl = wave;
            int nfbase = (c0 & 127) >> 4;
            size_t fbase = (((size_t)bhw * 32 + kbt) * 8 + (nfbase + nfl)) * 2;
#pragma unroll
            for (int g = 0; g < 2; g++) {
                bf16x4 a0 = *(const bf16x4*)(&tile[nfl * 16 + lrow][g * 32 + quad * 4]);
                bf16x4 a1 = *(const bf16x4*)(&tile[nfl * 16 + lrow][g * 32 + 16 + quad * 4]);
                bf16x8 w;
                w[0]=a0[0]; w[1]=a0[1]; w[2]=a0[2]; w[3]=a0[3];
                w[4]=a1[0]; w[5]=a1[1]; w[6]=a1[2]; w[7]=a1[3];
                *(bf16x8*)(Vf + (fbase + g) * 512 + lane * 8) = w;
            }
        }
        if (z < 2) __syncthreads();   // protect tile before next z overwrites
    }
}

// ---------------------------------------------------------------------------
// Kernel B: flash attention — CROSS-ITERATION SOFTWARE PIPELINE.
// R0-R6 established: 2048 waves = 2/SIMD is the min-traffic operating point;
// MFMA pipe busy 42% (19.4 SIMD-cyc per 16x16x32; floor ~35 µs); the idle
// 58% is in-order wave stall on the intra-iter chain QK->exp2->pack->PV.
// Fix: PV(t) and QK(t+1) are independent. K prefetched depth-3 (4 rotating
// LDS buffers; K(t+1) resident during iter t). Body interleaves
//   QK(t+1)s01 / exp2 / PV(t)g0 / exp2 / QK(t+1)s23 / exp2 / PV(t)g1 / exp2
// so every exp2 result is consumed a full iteration later and sits between
// independent MFMA clusters. vmcnt: PV's V-use drains older K-DMAs; the
// end-of-iter vmcnt(4) leaves exactly K(t+3) in flight (never drains the
// prefetch). Same P formula, same MFMA order per accumulator ->
// bit-identical output. LDS 73728 B (2 blocks/CU); V from global (R3).
// ---------------------------------------------------------------------------
__global__ __launch_bounds__(256, 2) void flash_attn(const bf16* __restrict__ Qf,
                                                     const bf16* __restrict__ Kf,
                                                     const bf16* __restrict__ Vf,
                                                     const float* __restrict__ mbias,
                                                     const int* __restrict__ mask,
                                                     bf16* __restrict__ ctxf) {
    __shared__ bf16 sm[32768];     // 4 rotating K buffers x 8192 elems (16 KB)
    __shared__ float mbL[2048];    // mbias row (8 KB); LDS total 73728 B

    int tid = threadIdx.x;
    int wave = tid >> 6, lane = tid & 63;
    int lrow = lane & 15, quad = lane >> 4;
    // XCD swizzle: 512 blocks = 8 xcd * (4 bh * 16 qblk)
    int bid = blockIdx.x;
    int xcd = bid & 7, seq = bid >> 3;          // seq 0..63
    int bh  = xcd * 4 + (seq >> 4);             // 0..31
    int qblk = seq & 15;                        // 0..15
    int b  = bh >> 4;
    int q0 = qblk * 128 + wave * 32;

    const float* mbp = mbias + b * N_;
    const bf16* kbase = Kf + (size_t)bh * 262144;
    const bf16* vbase = Vf + (size_t)bh * 262144 + lane * 8;

    // Q B-frags from Qf (coalesced 16B loads), held all loop
    bf16x8 qf[2][4];
#pragma unroll
    for (int u = 0; u < 2; u++)
#pragma unroll
        for (int kf = 0; kf < 4; kf++)
            qf[u][kf] = *(const bf16x8*)(Qf + (size_t)(((size_t)bh * 128 + (q0 >> 4) + u) * 4 + kf) * 512 + lane * 8);

    bf16x8 ones;
#pragma unroll
    for (int j = 0; j < 8; j++) ones[j] = (bf16)1.0f;

    floatx4 zero4 = {0.f, 0.f, 0.f, 0.f};
    floatx4 O[2][8];
#pragma unroll
    for (int u = 0; u < 2; u++)
#pragma unroll
        for (int nf = 0; nf < 8; nf++) O[u][nf] = zero4;
    floatx4 Oext[2] = {zero4, zero4};   // row sums l[q] via ones-MFMA

    const float scale = 0.12751742f;    // (1/sqrt(128)) * log2(e)

    // ---- prologue: DMA K(0),K(1),K(2) into buf0..2 + mbias; drain once ----
#pragma unroll
    for (int tt = 0; tt < 3; tt++) {
#pragma unroll
        for (int i = 0; i < 4; i++) {
            int seg = wave * 4 + i;            // 0..15, 1KB each
            load_lds16(kbase + (size_t)tt * 8192 + seg * 512 + lane * 8,
                       &sm[tt * 8192 + seg * 512]);
        }
    }
#pragma unroll
    for (int i = 0; i < 2; i++) {
        int seg = wave * 2 + i;                // 0..7, 256 floats (1KB) each
        load_lds16((const bf16*)(mbp + seg * 256) + lane * 8, (bf16*)(mbL + seg * 256));
    }
    __builtin_amdgcn_s_waitcnt(WAITCNT_VM(0));
    __builtin_amdgcn_s_barrier();

    // ---- prologue compute: QK(0) -> pa/pb (keys 0..31 / 32..63) ----
    bf16x8 pa[2], pb[2];
#pragma unroll
    for (int s = 0; s < 4; s++) {
        floatx4 S0 = zero4, S1 = zero4;
        __builtin_amdgcn_s_setprio(1);
#pragma unroll
        for (int kf = 0; kf < 4; kf++) {
            bf16x8 kfr = *(const bf16x8*)(&sm[((s * 4 + kf) * 64 + lane) * 8]);
            S0 = MFMA32K(kfr, qf[0][kf], S0);
            S1 = MFMA32K(kfr, qf[1][kf], S1);
        }
        __builtin_amdgcn_s_setprio(0);
        float4 mb4 = *(const float4*)(mbL + s * 16 + quad * 4);
        const float* mbr = (const float*)&mb4;
        int o = (s & 1) * 4;
#pragma unroll
        for (int r = 0; r < 4; r++) {
            float p0 = __builtin_amdgcn_exp2f(fmaf(S0[r], scale, mbr[r]));
            float p1 = __builtin_amdgcn_exp2f(fmaf(S1[r], scale, mbr[r]));
            if (s < 2) { pa[0][o + r] = (bf16)p0; pa[1][o + r] = (bf16)p1; }
            else       { pb[0][o + r] = (bf16)p0; pb[1][o + r] = (bf16)p1; }
        }
    }

    for (int t = 0; t < 32; t++) {
        // ---- V(t) global->reg (consumed in PV below; L2 latency hidden
        // under the QK(t+1) MFMA cluster) ----
        const bf16* vsrc = vbase + (size_t)t * 8192;
        bf16x8 vreg[16];
#pragma unroll
        for (int f = 0; f < 16; f++)
            vreg[f] = *(const bf16x8*)(vsrc + f * 512);

        // ---- DMA K(t+3) into the buffer freed two barriers ago ----
        if (t < 29) {
            int dst = ((t + 3) & 3) << 13;
            const bf16* ksrc = kbase + (size_t)(t + 3) * 8192;
#pragma unroll
            for (int i = 0; i < 4; i++) {
                int seg = wave * 4 + i;
                load_lds16(ksrc + seg * 512 + lane * 8, &sm[dst + seg * 512]);
            }
        }

        int nb = ((t + 1) & 3) << 13;          // buffer holding K(t+1)
        int tn = t + 1;
        bf16x8 pan[2], pbn[2];
        floatx4 Sa0, Sa1, Sb0, Sb1;

        if (t < 31) {
            // ---- QK(t+1) s=0,1 ----
            Sa0 = zero4; Sa1 = zero4; Sb0 = zero4; Sb1 = zero4;
            __builtin_amdgcn_s_setprio(1);
#pragma unroll
            for (int kf = 0; kf < 4; kf++) {
                bf16x8 kfr = *(const bf16x8*)(&sm[nb + ((0 * 4 + kf) * 64 + lane) * 8]);
                Sa0 = MFMA32K(kfr, qf[0][kf], Sa0);
                Sa1 = MFMA32K(kfr, qf[1][kf], Sa1);
            }
#pragma unroll
            for (int kf = 0; kf < 4; kf++) {
                bf16x8 kfr = *(const bf16x8*)(&sm[nb + ((1 * 4 + kf) * 64 + lane) * 8]);
                Sb0 = MFMA32K(kfr, qf[0][kf], Sb0);
                Sb1 = MFMA32K(kfr, qf[1][kf], Sb1);
            }
            __builtin_amdgcn_s_setprio(0);
            // exp2 s=0 -> pan[.][0..3] (result needed only next iter)
            float4 mb4 = *(const float4*)(mbL + tn * 64 + 0 * 16 + quad * 4);
            const float* mbr = (const float*)&mb4;
#pragma unroll
            for (int r = 0; r < 4; r++) {
                pan[0][r] = (bf16)__builtin_amdgcn_exp2f(fmaf(Sa0[r], scale, mbr[r]));
                pan[1][r] = (bf16)__builtin_amdgcn_exp2f(fmaf(Sa1[r], scale, mbr[r]));
            }
        }

        // ---- PV(t) g0 (independent of the QK(t+1) stream above) ----
        __builtin_amdgcn_s_setprio(1);
        Oext[0] = MFMA32K(ones, pa[0], Oext[0]);
        Oext[1] = MFMA32K(ones, pa[1], Oext[1]);
#pragma unroll
        for (int nf = 0; nf < 8; nf++) {
            O[0][nf] = MFMA32K(vreg[nf * 2], pa[0], O[0][nf]);
            O[1][nf] = MFMA32K(vreg[nf * 2], pa[1], O[1][nf]);
        }
        __builtin_amdgcn_s_setprio(0);

        if (t < 31) {
            // exp2 s=1 -> pan[.][4..7]
            float4 mb4 = *(const float4*)(mbL + tn * 64 + 1 * 16 + quad * 4);
            const float* mbr = (const float*)&mb4;
#pragma unroll
            for (int r = 0; r < 4; r++) {
                pan[0][4 + r] = (bf16)__builtin_amdgcn_exp2f(fmaf(Sb0[r], scale, mbr[r]));
                pan[1][4 + r] = (bf16)__builtin_amdgcn_exp2f(fmaf(Sb1[r], scale, mbr[r]));
            }
            // ---- QK(t+1) s=2,3 ----
            Sa0 = zero4; Sa1 = zero4; Sb0 = zero4; Sb1 = zero4;
            __builtin_amdgcn_s_setprio(1);
#pragma unroll
            for (int kf = 0; kf < 4; kf++) {
                bf16x8 kfr = *(const bf16x8*)(&sm[nb + ((2 * 4 + kf) * 64 + lane) * 8]);
                Sa0 = MFMA32K(kfr, qf[0][kf], Sa0);
                Sa1 = MFMA32K(kfr, qf[1][kf], Sa1);
            }
#pragma unroll
            for (int kf = 0; kf < 4; kf++) {
                bf16x8 kfr = *(const bf16x8*)(&sm[nb + ((3 * 4 + kf) * 64 + lane) * 8]);
                Sb0 = MFMA32K(kfr, qf[0][kf], Sb0);
                Sb1 = MFMA32K(kfr, qf[1][kf], Sb1);
            }
            __builtin_amdgcn_s_setprio(0);
            // exp2 s=2 -> pbn[.][0..3]
            float4 mb4b = *(const float4*)(mbL + tn * 64 + 2 * 16 + quad * 4);
            const float* mbr2 = (const float*)&mb4b;
#pragma unroll
            for (int r = 0; r < 4; r++) {
                pbn[0][r] = (bf16)__builtin_amdgcn_exp2f(fmaf(Sa0[r], scale, mbr2[r]));
                pbn[1][r] = (bf16)__builtin_amdgcn_exp2f(fmaf(Sa1[r], scale, mbr2[r]));
            }
        }

        // ---- PV(t) g1 ----
        __builtin_amdgcn_s_setprio(1);
        Oext[0] = MFMA32K(ones, pb[0], Oext[0]);
        Oext[1] = MFMA32K(ones, pb[1], Oext[1]);
#pragma unroll
        for (int nf = 0; nf < 8; nf++) {
            O[0][nf] = MFMA32K(vreg[nf * 2 + 1], pb[0], O[0][nf]);
            O[1][nf] = MFMA32K(vreg[nf * 2 + 1], pb[1], O[1][nf]);
        }
        __builtin_amdgcn_s_setprio(0);

        if (t < 31) {
            // exp2 s=3 -> pbn[.][4..7]; rotate pipeline regs
            float4 mb4 = *(const float4*)(mbL + tn * 64 + 3 * 16 + quad * 4);
            const float* mbr = (const float*)&mb4;
#pragma unroll
            for (int r = 0; r < 4; r++) {
                pbn[0][4 + r] = (bf16)__builtin_amdgcn_exp2f(fmaf(Sb0[r], scale, mbr[r]));
                pbn[1][4 + r] = (bf16)__builtin_amdgcn_exp2f(fmaf(Sb1[r], scale, mbr[r]));
            }
#pragma unroll
            for (int u = 0; u < 2; u++) { pa[u] = pan[u]; pb[u] = pbn[u]; }
        }

        // counted wait: leaves exactly K(t+3)'s 4 DMAs in flight (the V(t)
        // loads are older and already drained by their PV use).
        __builtin_amdgcn_s_waitcnt(WAITCNT_VM(4));
        __builtin_amdgcn_s_barrier();
    }

    // ---- epilogue: normalize + DIRECT permuted-concat A-frag stores ----
    const int* mp = mask + b * N_;
    int h4 = (bh & 15) * 4;
    size_t qtb = (size_t)b * 128 + (q0 >> 4);
#pragma unroll
    for (int u = 0; u < 2; u++) {
        float lsum = Oext[u][0];
        int q = q0 + u * 16 + lrow;
        float rl = (mp[q] && lsum > 0.f) ? (1.0f / lsum) : 0.f;
#pragma unroll
        for (int g = 0; g < 4; g++) {
            bf16x8 w;
#pragma unroll
            for (int j = 0; j < 4; j++) {
                w[j]     = (bf16)(O[u][2 * g][j]     * rl);
                w[j + 4] = (bf16)(O[u][2 * g + 1][j] * rl);
            }
            *(bf16x8*)(ctxf + ((qtb + u) * 64 + h4 + g) * 512 + lane * 8) = w;
        }
    }
}

// ---------------------------------------------------------------------------
// Kernel C: out = ctx @ Wo + bo, fp32 out. SPLIT-K x2 (best measured form)
// + XCD-aware flat-grid swizzle: the 4 ct-blocks sharing a qt's A-tile are
// 8 bids apart (same XCD under round-robin dispatch), and each XCD owns a
// contiguous qt range -> A reads become L2-local instead of L3-replicated.
// ---------------------------------------------------------------------------
__global__ __launch_bounds__(128) void out_proj(const bf16* __restrict__ ctxf,
                                                const bf16* __restrict__ Wof,
                                                const float* __restrict__ bo,
                                                float* __restrict__ out) {
    __shared__ float red[512];         // wave1 partials: [nf2][r4][lane64]
    int tid = threadIdx.x;
    int wave = tid >> 6, lane = tid & 63;
    int lrow = lane & 15, quad = lane >> 4;
    // 1024 blocks = 8 xcd * (32 qt * 4 ct2)
    int bid = blockIdx.x;
    int xcd = bid & 7, idx = bid >> 3;          // idx 0..127
    int qt = xcd * 32 + (idx >> 2);             // 16-row tile
    int ct = (idx & 3) * 2;                     // two 16-col tiles
    int r0 = qt * 16, c0 = ct * 16;

    floatx4 zero4 = {0.f, 0.f, 0.f, 0.f};
    floatx4 acc[2] = {zero4, zero4};
    const bf16* ap = ctxf + ((size_t)qt * 64 + wave * 32) * 512 + lane * 8;
    const bf16* b0 = Wof + ((size_t)ct * 64 + wave * 32) * 512 + lane * 8;
    const bf16* b1 = b0 + (size_t)64 * 512;
#pragma unroll 4
    for (int kf = 0; kf < 32; kf++) {
        bf16x8 a  = *(const bf16x8*)(ap + (size_t)kf * 512);
        bf16x8 w0 = *(const bf16x8*)(b0 + (size_t)kf * 512);
        bf16x8 w1 = *(const bf16x8*)(b1 + (size_t)kf * 512);
        acc[0] = MFMA32K(a, w0, acc[0]);
        acc[1] = MFMA32K(a, w1, acc[1]);
    }
    if (wave == 1) {
#pragma unroll
        for (int nf = 0; nf < 2; nf++)
#pragma unroll
            for (int r = 0; r < 4; r++)
                red[nf * 256 + r * 64 + lane] = acc[nf][r];
    }
    __syncthreads();
    if (wave == 0) {
#pragma unroll
        for (int nf = 0; nf < 2; nf++) {
            int col = c0 + nf * 16 + lrow;
            float bv = bo[col];
#pragma unroll
            for (int r = 0; r < 4; r++) {
                int m = r0 + quad * 4 + r;
                out[(size_t)m * 128 + col] = acc[nf][r] + red[nf * 256 + r * 64 + lane] + bv;
            }
        }
    }
}

// ---------------------------------------------------------------------------
extern "C" void kernel_launch(void* const* d_in, const int* in_sizes, int n_in,
                              void* d_out, int out_size, void* d_ws, size_t ws_size,
                              hipStream_t stream) {
    const float* x    = (const float*)d_in[0];
    const int*   mask = (const int*)d_in[1];
    const float* Wq   = (const float*)d_in[2];
    const float* bq   = (const float*)d_in[3];
    const float* Wk   = (const float*)d_in[4];
    const float* bk   = (const float*)d_in[5];
    const float* Wv   = (const float*)d_in[6];
    const float* bv   = (const float*)d_in[7];
    const float* Wo   = (const float*)d_in[8];
    const float* bo   = (const float*)d_in[9];
    float* out = (float*)d_out;

    char* ws = (char*)d_ws;
    size_t off = 0;
    bf16* Wqf = (bf16*)(ws + off); off += (size_t)262144 * 2;
    bf16* Wkf = (bf16*)(ws + off); off += (size_t)262144 * 2;
    bf16* Wvf = (bf16*)(ws + off); off += (size_t)262144 * 2;
    bf16* Wof = (bf16*)(ws + off); off += (size_t)262144 * 2;
    bf16* xf  = (bf16*)(ws + off); off += (size_t)524288 * 2;
    size_t qkv_elems = (size_t)BH_ * N_ * 128;           // 8.4M
    bf16* Qf  = (bf16*)(ws + off); off += qkv_elems * 2; // fragment-major
    bf16* Kf  = (bf16*)(ws + off); off += qkv_elems * 2;
    bf16* Vf  = (bf16*)(ws + off); off += qkv_elems * 2;
    bf16* ctxf = (bf16*)(ws + off); off += (size_t)M_ * ALL_ * 2;
    float* mbias = (float*)(ws + off); off += (size_t)B_ * N_ * 4;
    (void)ws_size; (void)in_sizes; (void)n_in; (void)out_size;

    prep_weights<<<368, 256, 0, stream>>>(x, Wq, Wk, Wv, Wo, mask,
                                          Wqf, Wkf, Wvf, Wof, xf, mbias);

    qkv_proj<<<dim3(64, 32), 256, 0, stream>>>(xf, bq, bk, bv, Wqf, Wkf, Wvf,
                                               Qf, Kf, Vf);

    flash_attn<<<512, 256, 0, stream>>>(Qf, Kf, Vf, mbias, mask, ctxf);

    out_proj<<<1024, 128, 0, stream>>>(ctxf, Wof, bo, out);
}